// Round 10
// baseline (354.894 us; speedup 1.0000x reference)
//
#include <hip/hip_runtime.h>

// Fused RMSNorm(Q,K) + NeoX RoPE + V passthrough for packed QKV. All f32.
// Single kernel. Each block (256 thr) handles 4 tokens:
//   prologue: 256 threads compute the 4-token cos/sin table (64 freqs each)
//   into 2 KB LDS with the exact reference f32 phase chain (f64 exp2 for
//   inv_freq; rint+f64-mulsub range reduction). One barrier, then pure
//   streaming: 16-lane group per head, lane l owns the rope pair
//   (x1[l*4..+4), x2[l*4..+4)) via two coalesced float4 loads.
// Stores are non-temporal (output is touch-once) via clang ext-vector type
// (HIP's float4 class is rejected by __builtin_nontemporal_store).

namespace {

constexpr int kNumQ = 32;
constexpr int kNumK = 8;
constexpr int kHead = 128;
constexpr int kRow  = (kNumQ + 2 * kNumK) * kHead;  // 6144
constexpr int kHalf = 64;                            // rotary_dim/2
constexpr int kQK   = kNumQ + kNumK;                 // 40 heads get norm+rope
constexpr int kTPB  = 4;                             // tokens per block

typedef float f32x4 __attribute__((ext_vector_type(4)));

__device__ __forceinline__ void nt_store4(float* p, float x, float y, float z,
                                          float w) {
  f32x4 v;
  v.x = x; v.y = y; v.z = z; v.w = w;
  __builtin_nontemporal_store(v, reinterpret_cast<f32x4*>(p));
}

__global__ __launch_bounds__(256) void rope_qknorm_kernel(
    const float* __restrict__ qkv,
    const float* __restrict__ qw,
    const float* __restrict__ kw,
    const int* __restrict__ positions,
    float* __restrict__ out,
    int tokens) {
  const int tid = threadIdx.x;
  const int t0  = blockIdx.x * kTPB;

  __shared__ float s_cos[kTPB][kHalf];
  __shared__ float s_sin[kTPB][kHalf];

  {
    // One phase per thread: tl = tid>>6 (token in block), i = tid&63 (freq).
    const int tl = tid >> 6;
    const int i  = tid & 63;
    const int t  = t0 + tl;
    if (t < tokens) {
      // Reference chain: inv_freq = f32(1/10000^(i/64)); phase = f32(pos*inv_freq);
      // accurate sin/cos of that f32 phase via exact rint+f64 reduction.
      const double log2b = 13.287712379549449629;  // log2(10000)
      const float p = (float)exp2((double)i * (log2b / 64.0));
      const float inv_freq = 1.0f / p;
      const float phase = (float)positions[t] * inv_freq;  // f32 round = ref
      const float k = rintf(phase * 0.15915494309189535f); // 1/(2pi)
      const double r = (double)phase - (double)k * 6.283185307179586476925287;
      const float pr = (float)r;                           // |pr| <= pi + eps
      s_cos[tl][i] = cosf(pr);
      s_sin[tl][i] = sinf(pr);
    }
  }
  __syncthreads();

  const int g = tid >> 4;   // head-group id in block (0..15)
  const int l = tid & 15;   // lane in group; owns rope-pair elems [l*4, l*4+4)

  const float4 qw1 = *reinterpret_cast<const float4*>(qw + l * 4);
  const float4 qw2 = *reinterpret_cast<const float4*>(qw + kHalf + l * 4);
  const float4 kw1 = *reinterpret_cast<const float4*>(kw + l * 4);
  const float4 kw2 = *reinterpret_cast<const float4*>(kw + kHalf + l * 4);

  #pragma unroll
  for (int tl = 0; tl < kTPB; ++tl) {
    const int t = t0 + tl;
    if (t >= tokens) break;
    const float* row  = qkv + (size_t)t * kRow;
    float*       orow = out + (size_t)t * kRow;

    const float4 cz = *reinterpret_cast<const float4*>(&s_cos[tl][l * 4]);
    const float4 sz = *reinterpret_cast<const float4*>(&s_sin[tl][l * 4]);

    #pragma unroll
    for (int hb = 0; hb < 48; hb += 16) {
      const int h = hb + g;                        // head index 0..47
      const float* hp = row + h * kHead + l * 4;
      const float4 a = *reinterpret_cast<const float4*>(hp);          // x1
      const float4 b = *reinterpret_cast<const float4*>(hp + kHalf);  // x2
      float* op = orow + h * kHead + l * 4;

      if (h < kQK) {                               // wave-uniform branch
        const bool isQ = (h < kNumQ);
        const float4 w1 = isQ ? qw1 : kw1;
        const float4 w2 = isQ ? qw2 : kw2;

        float ss = a.x * a.x + a.y * a.y + a.z * a.z + a.w * a.w +
                   b.x * b.x + b.y * b.y + b.z * b.z + b.w * b.w;
        #pragma unroll
        for (int m = 1; m < 16; m <<= 1) ss += __shfl_xor(ss, m, 16);
        const float inv = rsqrtf(ss * (1.0f / 128.0f) + 1e-6f);

        const float y1x = a.x * inv * w1.x, y1y = a.y * inv * w1.y;
        const float y1z = a.z * inv * w1.z, y1w = a.w * inv * w1.w;
        const float y2x = b.x * inv * w2.x, y2y = b.y * inv * w2.y;
        const float y2z = b.z * inv * w2.z, y2w = b.w * inv * w2.w;

        nt_store4(op,
                  y1x * cz.x - y2x * sz.x, y1y * cz.y - y2y * sz.y,
                  y1z * cz.z - y2z * sz.z, y1w * cz.w - y2w * sz.w);
        nt_store4(op + kHalf,
                  y2x * cz.x + y1x * sz.x, y2y * cz.y + y1y * sz.y,
                  y2z * cz.z + y1z * sz.z, y2w * cz.w + y1w * sz.w);
      } else {
        // V heads: bit-exact passthrough.
        nt_store4(op, a.x, a.y, a.z, a.w);
        nt_store4(op + kHalf, b.x, b.y, b.z, b.w);
      }
    }
  }
}

}  // namespace

extern "C" void kernel_launch(void* const* d_in, const int* in_sizes, int n_in,
                              void* d_out, int out_size, void* d_ws, size_t ws_size,
                              hipStream_t stream) {
  const float* qkv     = (const float*)d_in[0];
  const float* qw      = (const float*)d_in[1];
  const float* kw      = (const float*)d_in[2];
  const int* positions = (const int*)d_in[3];
  float* out           = (float*)d_out;

  const int tokens = in_sizes[3];  // positions element count == NUM_TOKENS
  const int blocks = (tokens + kTPB - 1) / kTPB;  // 2048 @ 8192 tokens
  rope_qknorm_kernel<<<blocks, 256, 0, stream>>>(qkv, qw, kw, positions, out,
                                                 tokens);
}